// Round 1
// baseline (1145.611 us; speedup 1.0000x reference)
//
#include <hip/hip_runtime.h>
#include <hip/hip_bf16.h>
#include <stdint.h>

#define IN_F 4096
#define OUT_F 4096
#define BATCH 64
#define NTILES 256
#define ROWS_PER_TILE 16
#define BIN_CAP 16384u
#define THRESH 0.01f

typedef unsigned int u32;
typedef unsigned short u16;

// ws layout:
//   [0)       u32 gcursor[256]                 (1 KB)
//   [4096)    u16 xT[4096][64]  (bf16, gated)  (512 KB)
//   [528384)  uint2 packed[256 * BIN_CAP]      (32 MB)
static const size_t WS_CURSOR = 0;
static const size_t WS_XT = 4096;
static const size_t WS_PACKED = 4096 + 524288;
static const size_t WS_NEEDED = WS_PACKED + (size_t)NTILES * BIN_CAP * 8;

__global__ __launch_bounds__(256) void k_init(u32* __restrict__ gcursor) {
  gcursor[threadIdx.x] = threadIdx.x * BIN_CAP;
}

// gate + transpose + bf16-convert: xT[c][b] = bf16(x[b][c] > 0.01 ? x[b][c] : 0)
__global__ __launch_bounds__(256) void k_xt(const float* __restrict__ x, u16* __restrict__ xT) {
  __shared__ float tile[64][65];
  const int c0 = blockIdx.x * 64;
  const int lane = threadIdx.x & 63;
  const int sub = threadIdx.x >> 6;
#pragma unroll
  for (int j = 0; j < 16; ++j) {
    const int b = j * 4 + sub;
    tile[b][lane] = x[b * IN_F + c0 + lane];
  }
  __syncthreads();
#pragma unroll
  for (int j = 0; j < 16; ++j) {
    const int cl = j * 4 + sub;
    float v = tile[lane][cl];
    v = (v > THRESH) ? v : 0.0f;
    __hip_bfloat16 h = __float2bfloat16(v);
    xT[(size_t)(c0 + cl) * 64 + lane] = *reinterpret_cast<u16*>(&h);
  }
}

// bin NNZ records into 256 row-tiles; per-block LDS ranking for semi-coalesced writes
__global__ __launch_bounds__(256) void k_scatter(const int* __restrict__ rows,
                                                const int* __restrict__ cols,
                                                const float* __restrict__ vals,
                                                u32 nnz, u32* __restrict__ gcursor,
                                                uint2* __restrict__ packed) {
  __shared__ u32 cnt[NTILES];
  __shared__ u32 basep[NTILES];
  const u32 tid = threadIdx.x;
  cnt[tid] = 0;
  __syncthreads();
  const u32 start = blockIdx.x * 2048u;
  u32 mt[8]; float mv[8]; u32 rk[8]; u32 bt[8];
#pragma unroll
  for (int j = 0; j < 8; ++j) {
    const u32 i = start + (u32)j * 256u + tid;
    bt[j] = 0xffffffffu;
    if (i < nnz) {
      const u32 r = (u32)rows[i];
      const u32 c = (u32)cols[i];
      mv[j] = vals[i];
      const u32 t = r >> 4;
      bt[j] = t;
      mt[j] = (c << 4) | (r & 15u);
      rk[j] = atomicAdd(&cnt[t], 1u);
    }
  }
  __syncthreads();
  basep[tid] = atomicAdd(&gcursor[tid], cnt[tid]);
  __syncthreads();
#pragma unroll
  for (int j = 0; j < 8; ++j) {
    if (bt[j] != 0xffffffffu) {
      const u32 pos = basep[bt[j]] + rk[j];
      if (pos < (bt[j] + 1u) * BIN_CAP)  // statistically impossible overflow guard
        packed[pos] = make_uint2(mt[j], __float_as_uint(mv[j]));
    }
  }
}

// one block per 16-row tile; lane = batch; ds_add_f32 accumulation; plain stores out
__global__ __launch_bounds__(1024) void k_accum(const uint2* __restrict__ packed,
                                                const u32* __restrict__ gcursor,
                                                const u16* __restrict__ xT,
                                                const float* __restrict__ bias,
                                                float* __restrict__ out) {
  __shared__ float acc[ROWS_PER_TILE * 64];
  const int t = blockIdx.x;
  const int tid = threadIdx.x;
  acc[tid] = 0.0f;
  __syncthreads();
  u32 n = gcursor[t] - (u32)t * BIN_CAP;
  if (n > BIN_CAP) n = BIN_CAP;
  const uint2* __restrict__ bin = packed + (size_t)t * BIN_CAP;
  const int lane = tid & 63;
  const u32 wid = (u32)__builtin_amdgcn_readfirstlane(tid >> 6);  // 0..15, SGPR

  u32 k0 = wid * 8u;
  for (; k0 + 8u <= n; k0 += 16u * 8u) {
    uint2 p[8];
#pragma unroll
    for (int u = 0; u < 8; ++u) p[u] = bin[k0 + u];  // wave-uniform -> one scalar 64B line
    float xv[8];
#pragma unroll
    for (int u = 0; u < 8; ++u) {
      const u32 c = p[u].x >> 4;
      xv[u] = __uint_as_float((u32)xT[c * 64 + lane] << 16);  // coalesced 128B bf16 row
    }
#pragma unroll
    for (int u = 0; u < 8; ++u) {
      const u32 r = p[u].x & 15u;
      atomicAdd(&acc[r * 64 + lane], __uint_as_float(p[u].y) * xv[u]);  // ds_add_f32
    }
  }
  // tail (at most one wave straddles n)
  for (u32 k = k0; k < n; ++k) {
    const uint2 p = bin[k];
    const u32 c = p.x >> 4;
    const u32 r = p.x & 15u;
    const float xv = __uint_as_float((u32)xT[c * 64 + lane] << 16);
    atomicAdd(&acc[r * 64 + lane], __uint_as_float(p.y) * xv);
  }
  __syncthreads();
  const int r = tid >> 6;
  const int b = tid & 63;
  const int gr = t * ROWS_PER_TILE + r;
  out[(size_t)b * OUT_F + gr] = acc[tid] + bias[gr];
}

// ---- fallback path (only if ws too small): correct but slow ----
__global__ __launch_bounds__(256) void k_bias_init(const float* __restrict__ bias,
                                                   float* __restrict__ out) {
  const int i = blockIdx.x * 256 + threadIdx.x;
  if (i < BATCH * OUT_F) out[i] = bias[i & (OUT_F - 1)];
}

__global__ __launch_bounds__(256) void k_fallback(const int* __restrict__ rows,
                                                  const int* __restrict__ cols,
                                                  const float* __restrict__ vals,
                                                  const float* __restrict__ x,
                                                  float* __restrict__ out, int nnz) {
  const int gw = (int)(((u32)blockIdx.x * blockDim.x + threadIdx.x) >> 6);
  const int lane = threadIdx.x & 63;
  const int nw = (int)(((u32)gridDim.x * blockDim.x) >> 6);
  for (int i = gw; i < nnz; i += nw) {
    const int r = rows[i];
    const int c = cols[i];
    const float v = vals[i];
    const float xv = x[lane * IN_F + c];
    if (xv > THRESH) atomicAdd(&out[(size_t)lane * OUT_F + r], v * xv);
  }
}

extern "C" void kernel_launch(void* const* d_in, const int* in_sizes, int n_in,
                              void* d_out, int out_size, void* d_ws, size_t ws_size,
                              hipStream_t stream) {
  const float* x = (const float*)d_in[0];
  const int* rows = (const int*)d_in[1];
  const int* cols = (const int*)d_in[2];
  const float* vals = (const float*)d_in[3];
  const float* bias = (const float*)d_in[4];
  float* out = (float*)d_out;
  const int nnz = in_sizes[1];

  if (ws_size >= WS_NEEDED) {
    u32* gcursor = (u32*)((char*)d_ws + WS_CURSOR);
    u16* xT = (u16*)((char*)d_ws + WS_XT);
    uint2* packed = (uint2*)((char*)d_ws + WS_PACKED);
    k_init<<<1, 256, 0, stream>>>(gcursor);
    k_xt<<<IN_F / 64, 256, 0, stream>>>(x, xT);
    k_scatter<<<(nnz + 2047) / 2048, 256, 0, stream>>>(rows, cols, vals, (u32)nnz,
                                                       gcursor, packed);
    k_accum<<<NTILES, 1024, 0, stream>>>(packed, gcursor, xT, bias, out);
  } else {
    k_bias_init<<<(BATCH * OUT_F + 255) / 256, 256, 0, stream>>>(bias, out);
    k_fallback<<<4096, 256, 0, stream>>>(rows, cols, vals, x, out, nnz);
  }
}

// Round 2
// 122.825 us; speedup vs baseline: 9.3272x; 9.3272x over previous
//
#include <hip/hip_runtime.h>
#include <hip/hip_bf16.h>
#include <stdint.h>

#define IN_F 4096
#define OUT_F 4096
#define BATCH 64
#define NBINS 4096
#define BIN_CAP 1024u
#define SBLOCKS 410          // 410 * 8192 = 3,358,720 >= NNZ
#define REC_PER_SB 8192
#define THRESH 0.01f

typedef unsigned int u32;
typedef unsigned short u16;

// ws layout:
//   [0)        u32 rowcnt[4096]            (16 KB)
//   [16384)    u16 xT[4096][64]            (512 KB)   gated bf16, xT[c][b]
//   [540672)   u32 partial[410][4096]      (6.7 MB)   per-block hist -> abs bases
//   [7258112)  u32 packed[4096*1024]       (16.8 MB)  {col:16 | bf16(val):16}
static const size_t WS_ROWCNT  = 0;
static const size_t WS_XT      = 16384;
static const size_t WS_PARTIAL = 16384 + 524288;
static const size_t WS_PACKED  = WS_PARTIAL + (size_t)SBLOCKS * NBINS * 4;
static const size_t WS_NEEDED  = WS_PACKED + (size_t)NBINS * BIN_CAP * 4;

// gate + transpose + bf16: xT[c][b] = bf16(x[b][c] > 0.01 ? x[b][c] : 0)
__global__ __launch_bounds__(256) void k_xt(const float* __restrict__ x, u16* __restrict__ xT) {
  __shared__ float tile[64][65];
  const int c0 = blockIdx.x * 64;
  const int lane = threadIdx.x & 63;
  const int sub = threadIdx.x >> 6;
#pragma unroll
  for (int j = 0; j < 16; ++j) {
    const int b = j * 4 + sub;
    tile[b][lane] = x[b * IN_F + c0 + lane];
  }
  __syncthreads();
#pragma unroll
  for (int j = 0; j < 16; ++j) {
    const int cl = j * 4 + sub;
    float v = tile[lane][cl];
    v = (v > THRESH) ? v : 0.0f;
    __hip_bfloat16 h = __float2bfloat16(v);
    xT[(size_t)(c0 + cl) * 64 + lane] = *reinterpret_cast<u16*>(&h);
  }
}

// per-block row histogram -> partial[b][r]
__global__ __launch_bounds__(1024) void k_hist(const int* __restrict__ rows, u32 nnz,
                                               u32* __restrict__ partial) {
  __shared__ u32 h[NBINS];
  const int tid = threadIdx.x;
#pragma unroll
  for (int j = 0; j < 4; ++j) h[tid + j * 1024] = 0;
  __syncthreads();
  const u32 base = blockIdx.x * REC_PER_SB;
#pragma unroll
  for (int j = 0; j < 8; ++j) {
    const u32 i = base + j * 1024u + tid;
    if (i < nnz) atomicAdd(&h[(u32)rows[i] & (NBINS - 1)], 1u);
  }
  __syncthreads();
  u32* p = partial + (size_t)blockIdx.x * NBINS;
#pragma unroll
  for (int j = 0; j < 4; ++j) p[tid + j * 1024] = h[tid + j * 1024];
}

// per-bin prefix over blocks: partial[b][r] := r*1024 + sum_{b'<b} cnt; rowcnt[r] = total
__global__ __launch_bounds__(256) void k_prefix(u32* __restrict__ partial,
                                                u32* __restrict__ rowcnt) {
  const u32 r = blockIdx.x * 256 + threadIdx.x;  // 16 blocks x 256
  u32 run = r << 10;
#pragma unroll 16
  for (int k = 0; k < SBLOCKS; ++k) {
    const u32 t = partial[(size_t)k * NBINS + r];
    partial[(size_t)k * NBINS + r] = run;
    run += t;
  }
  rowcnt[r] = run - (r << 10);
}

// re-read COO, rank within block via LDS, write packed {c<<16 | bf16(v)}
__global__ __launch_bounds__(1024) void k_scatter2(const int* __restrict__ rows,
                                                   const int* __restrict__ cols,
                                                   const float* __restrict__ vals, u32 nnz,
                                                   const u32* __restrict__ partial,
                                                   u32* __restrict__ packed) {
  __shared__ u32 cnt[NBINS];
  __shared__ u32 basel[NBINS];
  const int tid = threadIdx.x;
  const u32* p = partial + (size_t)blockIdx.x * NBINS;
#pragma unroll
  for (int j = 0; j < 4; ++j) {
    cnt[tid + j * 1024] = 0;
    basel[tid + j * 1024] = p[tid + j * 1024];
  }
  __syncthreads();
  const u32 base = blockIdx.x * REC_PER_SB;
#pragma unroll
  for (int j = 0; j < 8; ++j) {
    const u32 i = base + j * 1024u + tid;
    if (i < nnz) {
      const u32 r = (u32)rows[i] & (NBINS - 1);
      const u32 c = (u32)cols[i] & (IN_F - 1);
      const float v = vals[i];
      const u32 rk = atomicAdd(&cnt[r], 1u);
      const u32 slot = basel[r] + rk;
      __hip_bfloat16 h = __float2bfloat16(v);
      const u32 w = (c << 16) | (u32)(*reinterpret_cast<const u16*>(&h));
      if (slot < ((r + 1u) << 10)) packed[slot] = w;  // 7-sigma overflow guard
    }
  }
}

// one wave per row; lane = batch; acc in a register; readlane record broadcast
__global__ __launch_bounds__(256) void k_accum(const u32* __restrict__ packed,
                                               const u32* __restrict__ rowcnt,
                                               const u16* __restrict__ xT,
                                               const float* __restrict__ bias,
                                               float* __restrict__ out) {
  const int tid = threadIdx.x;
  const int lane = tid & 63;
  const int wid = tid >> 6;
  const u32 r = blockIdx.x * 4u + (u32)wid;
  u32 n = rowcnt[r];
  if (n > BIN_CAP) n = BIN_CAP;
  n = (u32)__builtin_amdgcn_readfirstlane((int)n);
  const u32* bin = packed + ((size_t)r << 10);
  float acc0 = 0.f, acc1 = 0.f;
  const u32 ns = (n + 63u) >> 6;
  u32 rec = bin[lane];  // safe even if n==0 (region allocated)
  for (u32 s = 0; s < ns; ++s) {
    const u32 rec_next = (s + 1u < ns) ? bin[(s + 1u) * 64u + lane] : 0u;
    const u32 cnt_here = n - s * 64u;  // wave-uniform
    if (cnt_here >= 64u) {
#pragma unroll
      for (int k = 0; k < 64; ++k) {
        const u32 rc = (u32)__builtin_amdgcn_readlane((int)rec, k);
        const u32 c = rc >> 16;
        const float v = __uint_as_float(rc << 16);
        const float xv = __uint_as_float((u32)xT[c * 64u + lane] << 16);
        if (k & 1) acc1 = fmaf(v, xv, acc1); else acc0 = fmaf(v, xv, acc0);
      }
    } else {
#pragma unroll
      for (int k = 0; k < 64; ++k) {
        const u32 rc = (u32)__builtin_amdgcn_readlane((int)rec, k);
        const u32 c = (rc >> 16) & (IN_F - 1);  // mask garbage
        const float v = ((u32)k < cnt_here) ? __uint_as_float(rc << 16) : 0.f;
        const float xv = __uint_as_float((u32)xT[c * 64u + lane] << 16);
        if (k & 1) acc1 = fmaf(v, xv, acc1); else acc0 = fmaf(v, xv, acc0);
      }
    }
    rec = rec_next;
  }
  out[(size_t)lane * OUT_F + r] = acc0 + acc1 + bias[r];
}

// ---- fallback path (only if ws too small): correct but slow ----
__global__ __launch_bounds__(256) void k_bias_init(const float* __restrict__ bias,
                                                   float* __restrict__ out) {
  const int i = blockIdx.x * 256 + threadIdx.x;
  if (i < BATCH * OUT_F) out[i] = bias[i & (OUT_F - 1)];
}

__global__ __launch_bounds__(256) void k_fallback(const int* __restrict__ rows,
                                                  const int* __restrict__ cols,
                                                  const float* __restrict__ vals,
                                                  const float* __restrict__ x,
                                                  float* __restrict__ out, int nnz) {
  const int gw = (int)(((u32)blockIdx.x * blockDim.x + threadIdx.x) >> 6);
  const int lane = threadIdx.x & 63;
  const int nw = (int)(((u32)gridDim.x * blockDim.x) >> 6);
  for (int i = gw; i < nnz; i += nw) {
    const int r = rows[i];
    const int c = cols[i];
    const float v = vals[i];
    const float xv = x[lane * IN_F + c];
    if (xv > THRESH) atomicAdd(&out[(size_t)lane * OUT_F + r], v * xv);
  }
}

extern "C" void kernel_launch(void* const* d_in, const int* in_sizes, int n_in,
                              void* d_out, int out_size, void* d_ws, size_t ws_size,
                              hipStream_t stream) {
  const float* x = (const float*)d_in[0];
  const int* rows = (const int*)d_in[1];
  const int* cols = (const int*)d_in[2];
  const float* vals = (const float*)d_in[3];
  const float* bias = (const float*)d_in[4];
  float* out = (float*)d_out;
  const int nnz = in_sizes[1];

  if (ws_size >= WS_NEEDED) {
    u32* rowcnt = (u32*)((char*)d_ws + WS_ROWCNT);
    u16* xT = (u16*)((char*)d_ws + WS_XT);
    u32* partial = (u32*)((char*)d_ws + WS_PARTIAL);
    u32* packed = (u32*)((char*)d_ws + WS_PACKED);
    k_xt<<<IN_F / 64, 256, 0, stream>>>(x, xT);
    k_hist<<<SBLOCKS, 1024, 0, stream>>>(rows, (u32)nnz, partial);
    k_prefix<<<NBINS / 256, 256, 0, stream>>>(partial, rowcnt);
    k_scatter2<<<SBLOCKS, 1024, 0, stream>>>(rows, cols, vals, (u32)nnz, partial, packed);
    k_accum<<<NBINS / 4, 256, 0, stream>>>(packed, rowcnt, xT, bias, out);
  } else {
    k_bias_init<<<(BATCH * OUT_F + 255) / 256, 256, 0, stream>>>(bias, out);
    k_fallback<<<4096, 256, 0, stream>>>(rows, cols, vals, x, out, nnz);
  }
}

// Round 3
// 89.018 us; speedup vs baseline: 12.8694x; 1.3798x over previous
//
#include <hip/hip_runtime.h>
#include <hip/hip_bf16.h>
#include <stdint.h>

#define IN_F 4096
#define OUT_F 4096
#define BATCH 64
#define NBKT 256
#define BKT_CAP 15872u       // per-bucket capacity; mean 13107, +24 sigma
#define SBLOCKS 410          // 410 * 8192 = 3,358,720 >= NNZ
#define THRESH 0.01f

typedef unsigned int u32;
typedef unsigned short u16;

// ws layout:
//   [0)       u32 gcursor[256]              (1 KB)
//   [4096)    u16 xT[4096][64]              (512 KB)  gated bf16, xT[c][b]
//   [528384)  u32 packed[256 * BKT_CAP]     (16.25 MB) {col:12|rowlo:4|bf16:16}
static const size_t WS_CURSOR = 0;
static const size_t WS_XT = 4096;
static const size_t WS_PACKED = 528384;
static const size_t WS_NEEDED = WS_PACKED + (size_t)NBKT * BKT_CAP * 4;

__global__ __launch_bounds__(256) void k_init(u32* __restrict__ gcursor) {
  gcursor[threadIdx.x] = (u32)threadIdx.x * BKT_CAP;
}

// gate + transpose + bf16: xT[c][b] = bf16(x[b][c] > 0.01 ? x[b][c] : 0)
__global__ __launch_bounds__(256) void k_xt(const float* __restrict__ x, u16* __restrict__ xT) {
  __shared__ float tile[64][65];
  const int c0 = blockIdx.x * 64;
  const int lane = threadIdx.x & 63;
  const int sub = threadIdx.x >> 6;
#pragma unroll
  for (int j = 0; j < 16; ++j) {
    const int b = j * 4 + sub;
    tile[b][lane] = x[b * IN_F + c0 + lane];
  }
  __syncthreads();
#pragma unroll
  for (int j = 0; j < 16; ++j) {
    const int cl = j * 4 + sub;
    float v = tile[lane][cl];
    v = (v > THRESH) ? v : 0.0f;
    __hip_bfloat16 h = __float2bfloat16(v);
    xT[(size_t)(c0 + cl) * 64 + lane] = *reinterpret_cast<u16*>(&h);
  }
}

// bin into 256 coarse buckets (16 rows each); 2-pass LDS rank -> ~128B runs per bucket
__global__ __launch_bounds__(1024) void k_scatter(const int* __restrict__ rows,
                                                  const int* __restrict__ cols,
                                                  const float* __restrict__ vals, u32 nnz,
                                                  u32* __restrict__ gcursor,
                                                  u32* __restrict__ packed) {
  __shared__ u32 cnt[NBKT];
  __shared__ u32 basep[NBKT];
  const int tid = threadIdx.x;
  if (tid < NBKT) cnt[tid] = 0;
  __syncthreads();
  const u32 base = blockIdx.x * 8192u;
  u32 rec[8]; u32 bkt[8];
#pragma unroll
  for (int j = 0; j < 8; ++j) {
    const u32 i = base + (u32)j * 1024u + tid;
    bkt[j] = 0xffffffffu;
    if (i < nnz) {
      const u32 r = (u32)rows[i] & 4095u;
      const u32 c = (u32)cols[i] & 4095u;
      const float v = vals[i];
      __hip_bfloat16 h = __float2bfloat16(v);
      rec[j] = (c << 20) | ((r & 15u) << 16) | (u32)(*reinterpret_cast<const u16*>(&h));
      bkt[j] = r >> 4;
      atomicAdd(&cnt[bkt[j]], 1u);
    }
  }
  __syncthreads();
  if (tid < NBKT) {
    basep[tid] = atomicAdd(&gcursor[tid], cnt[tid]);
    cnt[tid] = 0;  // reuse as live rank cursor
  }
  __syncthreads();
#pragma unroll
  for (int j = 0; j < 8; ++j) {
    if (bkt[j] != 0xffffffffu) {
      const u32 rk = atomicAdd(&cnt[bkt[j]], 1u);
      const u32 slot = basep[bkt[j]] + rk;
      if (slot < (bkt[j] + 1u) * BKT_CAP) packed[slot] = rec[j];  // ~impossible overflow
    }
  }
}

// one block per bucket: LDS counting-sort into 16 rows, then one wave per row,
// register accumulator, readlane record broadcast (proven round-2 inner loop)
__global__ __launch_bounds__(1024) void k_accum(const u32* __restrict__ packed,
                                                const u32* __restrict__ gcursor,
                                                const u16* __restrict__ xT,
                                                const float* __restrict__ bias,
                                                float* __restrict__ out) {
  __shared__ u32 sorted[BKT_CAP];   // 62 KB
  __shared__ u32 wcnt[16 * 17];     // [wave][row], padded
  __shared__ u32 rowstart[16];
  __shared__ u32 rowlen[16];
  const int tid = threadIdx.x;
  const int lane = tid & 63;
  const int wid = tid >> 6;
  const u32 t = blockIdx.x;
  u32 n = gcursor[t] - t * BKT_CAP;
  if (n > BKT_CAP) n = BKT_CAP;
  if (tid < 16 * 17) wcnt[tid] = 0;
  __syncthreads();

  // phase A: coalesced load of bucket + per-wave row histogram
  u32 rec[16];
#pragma unroll
  for (int j = 0; j < 16; ++j) {
    const u32 i = (u32)j * 1024u + tid;
    rec[j] = 0;
    if (i < n) {
      rec[j] = packed[(size_t)t * BKT_CAP + i];
      atomicAdd(&wcnt[wid * 17 + ((rec[j] >> 16) & 15u)], 1u);
    }
  }
  __syncthreads();

  // phase B: exclusive prefix (within-row over waves, then over rows)
  if (tid < 16) {
    u32 s = 0;
#pragma unroll
    for (int w = 0; w < 16; ++w) {
      const u32 v = wcnt[w * 17 + tid];
      wcnt[w * 17 + tid] = s;
      s += v;
    }
    rowlen[tid] = s;
  }
  __syncthreads();
  if (tid == 0) {
    u32 s = 0;
#pragma unroll
    for (int r2 = 0; r2 < 16; ++r2) { rowstart[r2] = s; s += rowlen[r2]; }
  }
  __syncthreads();

  // phase C: scatter records to row-sorted LDS positions
#pragma unroll
  for (int j = 0; j < 16; ++j) {
    const u32 i = (u32)j * 1024u + tid;
    if (i < n) {
      const u32 rl = (rec[j] >> 16) & 15u;
      const u32 pos = rowstart[rl] + atomicAdd(&wcnt[wid * 17 + rl], 1u);
      sorted[pos] = rec[j];
    }
  }
  __syncthreads();

  // phase D: wave wid owns row r = t*16 + wid; acc in registers
  const u32 rbase = (u32)__builtin_amdgcn_readfirstlane((int)rowstart[wid]);
  const u32 m = (u32)__builtin_amdgcn_readfirstlane((int)rowlen[wid]);
  float acc0 = 0.f, acc1 = 0.f;
  const u32 ns = (m + 63u) >> 6;
  u32 idx0 = rbase + (u32)lane;
  if (idx0 > BKT_CAP - 1u) idx0 = BKT_CAP - 1u;
  u32 cur = sorted[idx0];
  for (u32 s = 0; s < ns; ++s) {
    u32 nidx = rbase + (s + 1u) * 64u + (u32)lane;
    if (nidx > BKT_CAP - 1u) nidx = BKT_CAP - 1u;
    const u32 nxt = (s + 1u < ns) ? sorted[nidx] : 0u;
    const u32 here = m - s * 64u;  // wave-uniform
    if (here >= 64u) {
#pragma unroll
      for (int k = 0; k < 64; ++k) {
        const u32 rc = (u32)__builtin_amdgcn_readlane((int)cur, k);
        const u32 c = rc >> 20;
        const float v = __uint_as_float(rc << 16);
        const float xv = __uint_as_float((u32)xT[c * 64u + lane] << 16);
        if (k & 1) acc1 = fmaf(v, xv, acc1); else acc0 = fmaf(v, xv, acc0);
      }
    } else {
#pragma unroll
      for (int k = 0; k < 64; ++k) {
        const u32 rc = (u32)__builtin_amdgcn_readlane((int)cur, k);
        const u32 c = rc >> 20;
        const float v = ((u32)k < here) ? __uint_as_float(rc << 16) : 0.f;
        const float xv = __uint_as_float((u32)xT[c * 64u + lane] << 16);
        if (k & 1) acc1 = fmaf(v, xv, acc1); else acc0 = fmaf(v, xv, acc0);
      }
    }
    cur = nxt;
  }
  const u32 r = t * 16u + (u32)wid;
  out[(size_t)lane * OUT_F + r] = acc0 + acc1 + bias[r];
}

// ---- fallback path (only if ws too small): correct but slow ----
__global__ __launch_bounds__(256) void k_bias_init(const float* __restrict__ bias,
                                                   float* __restrict__ out) {
  const int i = blockIdx.x * 256 + threadIdx.x;
  if (i < BATCH * OUT_F) out[i] = bias[i & (OUT_F - 1)];
}

__global__ __launch_bounds__(256) void k_fallback(const int* __restrict__ rows,
                                                  const int* __restrict__ cols,
                                                  const float* __restrict__ vals,
                                                  const float* __restrict__ x,
                                                  float* __restrict__ out, int nnz) {
  const int gw = (int)(((u32)blockIdx.x * blockDim.x + threadIdx.x) >> 6);
  const int lane = threadIdx.x & 63;
  const int nw = (int)(((u32)gridDim.x * blockDim.x) >> 6);
  for (int i = gw; i < nnz; i += nw) {
    const int r = rows[i];
    const int c = cols[i];
    const float v = vals[i];
    const float xv = x[lane * IN_F + c];
    if (xv > THRESH) atomicAdd(&out[(size_t)lane * OUT_F + r], v * xv);
  }
}

extern "C" void kernel_launch(void* const* d_in, const int* in_sizes, int n_in,
                              void* d_out, int out_size, void* d_ws, size_t ws_size,
                              hipStream_t stream) {
  const float* x = (const float*)d_in[0];
  const int* rows = (const int*)d_in[1];
  const int* cols = (const int*)d_in[2];
  const float* vals = (const float*)d_in[3];
  const float* bias = (const float*)d_in[4];
  float* out = (float*)d_out;
  const int nnz = in_sizes[1];

  if (ws_size >= WS_NEEDED) {
    u32* gcursor = (u32*)((char*)d_ws + WS_CURSOR);
    u16* xT = (u16*)((char*)d_ws + WS_XT);
    u32* packed = (u32*)((char*)d_ws + WS_PACKED);
    k_init<<<1, 256, 0, stream>>>(gcursor);
    k_xt<<<IN_F / 64, 256, 0, stream>>>(x, xT);
    k_scatter<<<SBLOCKS, 1024, 0, stream>>>(rows, cols, vals, (u32)nnz, gcursor, packed);
    k_accum<<<NBKT, 1024, 0, stream>>>(packed, gcursor, xT, bias, out);
  } else {
    k_bias_init<<<(BATCH * OUT_F + 255) / 256, 256, 0, stream>>>(bias, out);
    k_fallback<<<4096, 256, 0, stream>>>(rows, cols, vals, x, out, nnz);
  }
}

// Round 5
// 70.635 us; speedup vs baseline: 16.2188x; 1.2603x over previous
//
#include <hip/hip_runtime.h>
#include <hip/hip_bf16.h>
#include <stdint.h>

#define IN_F 4096
#define OUT_F 4096
#define NBKT 256
#define BKT_CAP 15872u       // mean 13107, +24 sigma
#define SBLOCKS 410          // 410 * 8192 >= NNZ
#define THRESH 0.01f

typedef unsigned int u32;
typedef unsigned short u16;
typedef __attribute__((ext_vector_type(8))) short short8;   // 8 bf16 = 4 VGPR
typedef __attribute__((ext_vector_type(4))) float f32x4;

// ws layout:
//   [0)       u32 gcursor[256]               (1 KB)
//   [4096)    u16 xB[512][64][8]             (512 KB)  B-frag layout: ((k>>3)*64+b)*8+(k&7)
//   [528384)  u32 packed[256 * BKT_CAP]      (16.25 MB) {col:12|rowlo:4|bf16:16}
static const size_t WS_CURSOR = 0;
static const size_t WS_XB = 4096;
static const size_t WS_PACKED = 528384;
static const size_t WS_NEEDED = WS_PACKED + (size_t)NBKT * BKT_CAP * 4;

static __device__ __forceinline__ u16 f2bf(float v) {
  __hip_bfloat16 h = __float2bfloat16(v);
  return *reinterpret_cast<u16*>(&h);
}

__global__ __launch_bounds__(256) void k_init(u32* __restrict__ gcursor) {
  gcursor[threadIdx.x] = (u32)threadIdx.x * BKT_CAP;
}

// gate + bf16 + MFMA-B-fragment layout: xB[((k>>3)*64 + b)*8 + (k&7)] = bf16(gate(x[b][k]))
__global__ __launch_bounds__(256) void k_xb(const float* __restrict__ x, u16* __restrict__ xB) {
  const int tid = blockIdx.x * 256 + threadIdx.x;   // 32768 threads
  const int b = tid & 63;
  const int kg = tid >> 6;                          // 0..511
  const float* src = x + (size_t)b * IN_F + kg * 8;
  const f32x4 a0 = *reinterpret_cast<const f32x4*>(src);
  const f32x4 a1 = *reinterpret_cast<const f32x4*>(src + 4);
  short8 o;
#pragma unroll
  for (int e = 0; e < 4; ++e) {
    float v = a0[e]; v = (v > THRESH) ? v : 0.0f; o[e] = (short)f2bf(v);
  }
#pragma unroll
  for (int e = 0; e < 4; ++e) {
    float v = a1[e]; v = (v > THRESH) ? v : 0.0f; o[4 + e] = (short)f2bf(v);
  }
  *reinterpret_cast<short8*>(xB + ((size_t)kg * 64 + b) * 8) = o;   // coalesced 16B
}

// bin into 256 buckets (16 rows each); rank from the histogram atomic (1 LDS atomic/record)
__global__ __launch_bounds__(1024) void k_scatter(const int* __restrict__ rows,
                                                  const int* __restrict__ cols,
                                                  const float* __restrict__ vals, u32 nnz,
                                                  u32* __restrict__ gcursor,
                                                  u32* __restrict__ packed) {
  __shared__ u32 cnt[NBKT];
  __shared__ u32 basep[NBKT];
  const int tid = threadIdx.x;
  if (tid < NBKT) cnt[tid] = 0;
  __syncthreads();
  const u32 base = blockIdx.x * 8192u;
  u32 rec[8], bkt[8], rk[8];
#pragma unroll
  for (int j = 0; j < 8; ++j) {
    const u32 i = base + (u32)j * 1024u + tid;
    bkt[j] = 0xffffffffu;
    if (i < nnz) {
      const u32 r = (u32)rows[i] & 4095u;
      const u32 c = (u32)cols[i] & 4095u;
      rec[j] = (c << 20) | ((r & 15u) << 16) | (u32)f2bf(vals[i]);
      bkt[j] = r >> 4;
      rk[j] = atomicAdd(&cnt[bkt[j]], 1u);
    }
  }
  __syncthreads();
  if (tid < NBKT) basep[tid] = atomicAdd(&gcursor[tid], cnt[tid]);
  __syncthreads();
#pragma unroll
  for (int j = 0; j < 8; ++j) {
    if (bkt[j] != 0xffffffffu) {
      const u32 slot = basep[bkt[j]] + rk[j];
      if (slot < (bkt[j] + 1u) * BKT_CAP) packed[slot] = rec[j];   // ~24-sigma guard
    }
  }
}

// one block per bucket: K-quarter f32 LDS W-slice (ds_add scatter) -> dense MFMA
__global__ __launch_bounds__(1024) void k_accum(const u32* __restrict__ packed,
                                                const u32* __restrict__ gcursor,
                                                const u16* __restrict__ xB,
                                                const float* __restrict__ bias,
                                                float* __restrict__ out) {
  __shared__ float W[16 * 1024];   // 64 KB; reused as reduction scratch at the end
  const int tid = threadIdx.x;
  const int lane = tid & 63;
  const int w = tid >> 6;          // wave 0..15 : owns K-slice [w*64, w*64+64) per quarter
  const u32 t = blockIdx.x;
  u32 n = gcursor[t] - t * BKT_CAP;
  if (n > BKT_CAP) n = BKT_CAP;

  // preload this bucket's records (coalesced, L2)
  u32 rec[16];
#pragma unroll
  for (int j = 0; j < 16; ++j) {
    const u32 i = (u32)j * 1024u + tid;
    rec[j] = (i < n) ? packed[(size_t)t * BKT_CAP + i] : 0u;
  }

  f32x4 acc0 = {0.f, 0.f, 0.f, 0.f}, acc1 = {0.f, 0.f, 0.f, 0.f};
  f32x4 acc2 = {0.f, 0.f, 0.f, 0.f}, acc3 = {0.f, 0.f, 0.f, 0.f};
  const int row = lane & 15;       // A-frag row / C col index
  const int e8 = (lane >> 4) * 8;  // A/B-frag k sub-offset

  for (int q = 0; q < 4; ++q) {
    __syncthreads();               // previous quarter's A-reads done before re-zero
    const f32x4 z = {0.f, 0.f, 0.f, 0.f};
#pragma unroll
    for (int j = 0; j < 4; ++j)
      *reinterpret_cast<f32x4*>(&W[j * 4096 + tid * 4]) = z;
    __syncthreads();
    // scatter-add this quarter's records (f32: exact duplicate handling)
    // swizzle at 8-ELEMENT granularity: XOR bits >=3 only, so any aligned
    // 8-run [klb, klb+8) maps to the physical 8-run [klb^xor, klb^xor+8).
#pragma unroll
    for (int j = 0; j < 16; ++j) {
      const u32 i = (u32)j * 1024u + tid;
      if (i < n) {
        const u32 rc = rec[j];
        const u32 c = rc >> 20;
        if ((int)(c >> 10) == q) {
          const u32 rl = (rc >> 16) & 15u;
          const u32 cl = (c & 1023u) ^ ((rl & 7u) << 3);   // 8-elem XOR swizzle
          __hip_atomic_fetch_add(&W[rl * 1024u + cl], __uint_as_float(rc << 16),
                                 __ATOMIC_RELAXED, __HIP_MEMORY_SCOPE_WORKGROUP);
        }
      }
    }
    __syncthreads();
    // dense MFMA over this quarter; wave w covers local k [w*64, w*64+64)
#pragma unroll
    for (int s = 0; s < 2; ++s) {
      const int klb = w * 64 + s * 32 + e8;                 // 8-aligned local k
      const int sw = klb ^ ((row & 7) << 3);                // matches write swizzle
      const f32x4 wa = *reinterpret_cast<const f32x4*>(&W[row * 1024 + sw]);
      const f32x4 wb = *reinterpret_cast<const f32x4*>(&W[row * 1024 + (sw + 4)]);
      short8 af;
#pragma unroll
      for (int e = 0; e < 4; ++e) af[e] = (short)f2bf(wa[e]);
#pragma unroll
      for (int e = 0; e < 4; ++e) af[4 + e] = (short)f2bf(wb[e]);
      const int kabs = q * 1024 + klb;
      const u16* bp = xB + (size_t)(kabs >> 3) * 512 + (u32)(lane & 15) * 8;
      const short8 b0 = *reinterpret_cast<const short8*>(bp);
      const short8 b1 = *reinterpret_cast<const short8*>(bp + 128);
      const short8 b2 = *reinterpret_cast<const short8*>(bp + 256);
      const short8 b3 = *reinterpret_cast<const short8*>(bp + 384);
      acc0 = __builtin_amdgcn_mfma_f32_16x16x32_bf16(af, b0, acc0, 0, 0, 0);
      acc1 = __builtin_amdgcn_mfma_f32_16x16x32_bf16(af, b1, acc1, 0, 0, 0);
      acc2 = __builtin_amdgcn_mfma_f32_16x16x32_bf16(af, b2, acc2, 0, 0, 0);
      acc3 = __builtin_amdgcn_mfma_f32_16x16x32_bf16(af, b3, acc3, 0, 0, 0);
    }
  }
  __syncthreads();
  // write per-wave C partials to scratch: scr[((w*4+nt)*16 + crow)*16 + ccol]
  {
    const int ccol = lane & 15;                 // C col = lane&15 (m89-verified)
    const int rb = (lane >> 4) * 4;             // C row = (lane>>4)*4 + reg
#pragma unroll
    for (int qq = 0; qq < 4; ++qq) W[((w * 4 + 0) * 16 + rb + qq) * 16 + ccol] = acc0[qq];
#pragma unroll
    for (int qq = 0; qq < 4; ++qq) W[((w * 4 + 1) * 16 + rb + qq) * 16 + ccol] = acc1[qq];
#pragma unroll
    for (int qq = 0; qq < 4; ++qq) W[((w * 4 + 2) * 16 + rb + qq) * 16 + ccol] = acc2[qq];
#pragma unroll
    for (int qq = 0; qq < 4; ++qq) W[((w * 4 + 3) * 16 + rb + qq) * 16 + ccol] = acc3[qq];
  }
  __syncthreads();
  // reduce 16 wave-partials -> out(row rl, batch b); coalesced 64B store runs
  const int rl = tid & 15;
  const int b = tid >> 4;
  float sum = bias[t * 16u + rl];
#pragma unroll
  for (int w2 = 0; w2 < 16; ++w2)
    sum += W[((w2 * 4 + (b >> 4)) * 16 + rl) * 16 + (b & 15)];
  out[(size_t)b * OUT_F + t * 16u + rl] = sum;
}

// ---- fallback path (only if ws too small): correct but slow ----
__global__ __launch_bounds__(256) void k_bias_init(const float* __restrict__ bias,
                                                   float* __restrict__ out) {
  const int i = blockIdx.x * 256 + threadIdx.x;
  if (i < 64 * OUT_F) out[i] = bias[i & (OUT_F - 1)];
}

__global__ __launch_bounds__(256) void k_fallback(const int* __restrict__ rows,
                                                  const int* __restrict__ cols,
                                                  const float* __restrict__ vals,
                                                  const float* __restrict__ x,
                                                  float* __restrict__ out, int nnz) {
  const int gw = (int)(((u32)blockIdx.x * blockDim.x + threadIdx.x) >> 6);
  const int lane = threadIdx.x & 63;
  const int nw = (int)(((u32)gridDim.x * blockDim.x) >> 6);
  for (int i = gw; i < nnz; i += nw) {
    const int r = rows[i];
    const int c = cols[i];
    const float v = vals[i];
    const float xv = x[lane * IN_F + c];
    if (xv > THRESH) atomicAdd(&out[(size_t)lane * OUT_F + r], v * xv);
  }
}

extern "C" void kernel_launch(void* const* d_in, const int* in_sizes, int n_in,
                              void* d_out, int out_size, void* d_ws, size_t ws_size,
                              hipStream_t stream) {
  const float* x = (const float*)d_in[0];
  const int* rows = (const int*)d_in[1];
  const int* cols = (const int*)d_in[2];
  const float* vals = (const float*)d_in[3];
  const float* bias = (const float*)d_in[4];
  float* out = (float*)d_out;
  const int nnz = in_sizes[1];

  if (ws_size >= WS_NEEDED) {
    u32* gcursor = (u32*)((char*)d_ws + WS_CURSOR);
    u16* xB = (u16*)((char*)d_ws + WS_XB);
    u32* packed = (u32*)((char*)d_ws + WS_PACKED);
    k_init<<<1, 256, 0, stream>>>(gcursor);
    k_xb<<<128, 256, 0, stream>>>(x, xB);
    k_scatter<<<SBLOCKS, 1024, 0, stream>>>(rows, cols, vals, (u32)nnz, gcursor, packed);
    k_accum<<<NBKT, 1024, 0, stream>>>(packed, gcursor, xB, bias, out);
  } else {
    k_bias_init<<<(64 * OUT_F + 255) / 256, 256, 0, stream>>>(bias, out);
    k_fallback<<<4096, 256, 0, stream>>>(rows, cols, vals, x, out, nnz);
  }
}

// Round 6
// 60.228 us; speedup vs baseline: 19.0212x; 1.1728x over previous
//
#include <hip/hip_runtime.h>
#include <hip/hip_bf16.h>
#include <stdint.h>

#define IN_F 4096
#define OUT_F 4096
#define NBKT 256
#define SBLOCKS 410          // 410 * 8192 = 3,358,720 >= NNZ
#define REC_PER_SB 8192
#define SMAX 14336u          // bucket records cap: mean 13107, sigma 114, +10 sigma
#define THRESH 0.01f

typedef unsigned int u32;
typedef unsigned short u16;
typedef __attribute__((ext_vector_type(8))) short short8;   // 8 bf16 = 4 VGPR
typedef __attribute__((ext_vector_type(4))) float f32x4;

// ws layout:
//   [0)        u16 xB[512][64][8]            (512 KB)  B-frag layout: ((k>>3)*64+b)*8+(k&7)
//   [524288)   u32 offA[410][257]            (412 KB)  per-scatter-block bucket prefix
//   [950272)   u32 sortg[410][8192]          (13.4 MB) block-major bucket-sorted records
static const size_t WS_XB = 0;
static const size_t WS_OFFA = 524288;
static const size_t WS_SORT = 950272;
static const size_t WS_NEEDED = WS_SORT + (size_t)SBLOCKS * REC_PER_SB * 4;

static __device__ __forceinline__ u16 f2bf(float v) {
  __hip_bfloat16 h = __float2bfloat16(v);
  return *reinterpret_cast<u16*>(&h);
}

// gate + bf16 + MFMA-B-fragment layout: xB[((k>>3)*64 + b)*8 + (k&7)] = bf16(gate(x[b][k]))
__global__ __launch_bounds__(256) void k_xb(const float* __restrict__ x, u16* __restrict__ xB) {
  const int tid = blockIdx.x * 256 + threadIdx.x;   // 32768 threads
  const int b = tid & 63;
  const int kg = tid >> 6;                          // 0..511
  const float* src = x + (size_t)b * IN_F + kg * 8;
  const f32x4 a0 = *reinterpret_cast<const f32x4*>(src);
  const f32x4 a1 = *reinterpret_cast<const f32x4*>(src + 4);
  short8 o;
#pragma unroll
  for (int e = 0; e < 4; ++e) {
    float v = a0[e]; v = (v > THRESH) ? v : 0.0f; o[e] = (short)f2bf(v);
  }
#pragma unroll
  for (int e = 0; e < 4; ++e) {
    float v = a1[e]; v = (v > THRESH) ? v : 0.0f; o[4 + e] = (short)f2bf(v);
  }
  *reinterpret_cast<short8*>(xB + ((size_t)kg * 64 + b) * 8) = o;   // coalesced 16B
}

// block-major counting sort: each block sorts its 8192 records by bucket in LDS,
// dumps one coalesced 32KB segment + its 257-entry prefix. No global atomics,
// no scattered global stores, exact counts (no capacity guard).
__global__ __launch_bounds__(1024) void k_scatter(const int* __restrict__ rows,
                                                  const int* __restrict__ cols,
                                                  const float* __restrict__ vals, u32 nnz,
                                                  u32* __restrict__ offA,
                                                  u32* __restrict__ sortg) {
  __shared__ u32 cnt[NBKT];
  __shared__ u32 pref[NBKT + 1];
  __shared__ u32 srt[REC_PER_SB];   // 32 KB
  const int tid = threadIdx.x;
  const int lane = tid & 63;
  const int wid = tid >> 6;
  if (tid < NBKT) cnt[tid] = 0;
  __syncthreads();
  const u32 base = blockIdx.x * (u32)REC_PER_SB;
  u32 rec[8], bkt[8], rk[8];
#pragma unroll
  for (int j = 0; j < 8; ++j) {
    const u32 i = base + (u32)j * 1024u + tid;
    bkt[j] = 0xffffffffu;
    if (i < nnz) {
      const u32 r = (u32)rows[i] & 4095u;
      const u32 c = (u32)cols[i] & 4095u;
      rec[j] = (c << 20) | ((r & 15u) << 16) | (u32)f2bf(vals[i]);
      bkt[j] = r >> 4;
      rk[j] = atomicAdd(&cnt[bkt[j]], 1u);
    }
  }
  __syncthreads();
  // wave-0 exclusive prefix over 256 bins (4 bins/lane + wave scan)
  if (wid == 0) {
    u32 a[4]; u32 s = 0;
#pragma unroll
    for (int j = 0; j < 4; ++j) { a[j] = cnt[lane * 4 + j]; s += a[j]; }
    u32 x = s;
#pragma unroll
    for (int d = 1; d < 64; d <<= 1) {
      const u32 y = (u32)__shfl_up((int)x, d, 64);
      if (lane >= d) x += y;
    }
    u32 e = x - s;
#pragma unroll
    for (int j = 0; j < 4; ++j) { pref[lane * 4 + j] = e; e += a[j]; }
    if (lane == 63) pref[256] = e;   // block total
  }
  __syncthreads();
#pragma unroll
  for (int j = 0; j < 8; ++j)
    if (bkt[j] != 0xffffffffu) srt[pref[bkt[j]] + rk[j]] = rec[j];
  if (tid < NBKT + 1) offA[(size_t)blockIdx.x * (NBKT + 1) + tid] = pref[tid];
  __syncthreads();
  // coalesced segment dump (16B per thread per j)
  u32* dst = sortg + (size_t)blockIdx.x * REC_PER_SB;
#pragma unroll
  for (int j = 0; j < 2; ++j) {
    const int o = j * 4096 + tid * 4;
    const uint4 v = *reinterpret_cast<uint4*>(&srt[o]);
    *reinterpret_cast<uint4*>(&dst[o]) = v;   // garbage beyond total: never read
  }
}

// one block per bucket: gather 410 runs -> LDS staging -> quarter densify -> MFMA
__global__ __launch_bounds__(1024) void k_accum(const u32* __restrict__ sortg,
                                                const u32* __restrict__ offA,
                                                const u16* __restrict__ xB,
                                                const float* __restrict__ bias,
                                                float* __restrict__ out) {
  __shared__ float W[16 * 1024];    // 64 KB; reused as reduction scratch at the end
  __shared__ u32 S[SMAX];           // 56 KB record staging
  __shared__ u32 Gs[412], Gl[412], GP[418];
  const int tid = threadIdx.x;
  const int lane = tid & 63;
  const int w = tid >> 6;           // wave 0..15
  const u32 t = blockIdx.x;

  // per-run start/len for this bucket
  if (tid < SBLOCKS) {
    const u32 a = offA[(size_t)tid * (NBKT + 1) + t];
    const u32 b = offA[(size_t)tid * (NBKT + 1) + t + 1];
    Gs[tid] = (u32)tid * REC_PER_SB + a;
    Gl[tid] = b - a;
  } else if (tid < 412) { Gs[tid] = 0; Gl[tid] = 0; }
  __syncthreads();
  // wave-0 exclusive prefix over 410 run lengths (7 bins/lane + wave scan)
  if (w == 0) {
    u32 l[7]; u32 s = 0;
#pragma unroll
    for (int j = 0; j < 7; ++j) { const int idx = lane * 7 + j; l[j] = (idx < 412) ? Gl[idx] : 0; s += l[j]; }
    u32 x = s;
#pragma unroll
    for (int d = 1; d < 64; d <<= 1) {
      const u32 y = (u32)__shfl_up((int)x, d, 64);
      if (lane >= d) x += y;
    }
    u32 e = x - s;
#pragma unroll
    for (int j = 0; j < 7; ++j) { const int idx = lane * 7 + j; if (idx < 418) GP[idx] = e; e += l[j]; }
  }
  __syncthreads();
  u32 n = GP[SBLOCKS];
  if (n > SMAX) n = SMAX;   // ~10-sigma paranoia
  // gather runs (avg 32 records = 128 B each; independent -> deep MLP)
  for (int g = w; g < SBLOCKS; g += 16) {
    const u32 len = Gl[g], src = Gs[g], dst = GP[g];
    for (u32 k = (u32)lane; k < len; k += 64u) {
      const u32 d2 = dst + k;
      if (d2 < SMAX) S[d2] = sortg[src + k];
    }
  }
  __syncthreads();
  // preload records to VGPRs
  u32 rec[14];
#pragma unroll
  for (int j = 0; j < 14; ++j) {
    const u32 i = (u32)j * 1024u + tid;
    rec[j] = (i < n) ? S[i] : 0u;
  }

  f32x4 acc0 = {0.f, 0.f, 0.f, 0.f}, acc1 = {0.f, 0.f, 0.f, 0.f};
  f32x4 acc2 = {0.f, 0.f, 0.f, 0.f}, acc3 = {0.f, 0.f, 0.f, 0.f};
  const int row = lane & 15;       // A-frag row / C col index
  const int e8 = (lane >> 4) * 8;  // A/B-frag k sub-offset

  for (int q = 0; q < 4; ++q) {
    __syncthreads();               // previous quarter's A-reads done before re-zero
    const f32x4 z = {0.f, 0.f, 0.f, 0.f};
#pragma unroll
    for (int j = 0; j < 4; ++j)
      *reinterpret_cast<f32x4*>(&W[j * 4096 + tid * 4]) = z;
    __syncthreads();
    // scatter-add this quarter's records (f32: exact duplicate handling)
    // swizzle at 8-ELEMENT granularity: XOR bits >=3 only, so any aligned
    // 8-run [klb, klb+8) maps to the physical 8-run [klb^xor, klb^xor+8).
#pragma unroll
    for (int j = 0; j < 14; ++j) {
      const u32 i = (u32)j * 1024u + tid;
      if (i < n) {
        const u32 rc = rec[j];
        const u32 c = rc >> 20;
        if ((int)(c >> 10) == q) {
          const u32 rl = (rc >> 16) & 15u;
          const u32 cl = (c & 1023u) ^ ((rl & 7u) << 3);   // 8-elem XOR swizzle
          __hip_atomic_fetch_add(&W[rl * 1024u + cl], __uint_as_float(rc << 16),
                                 __ATOMIC_RELAXED, __HIP_MEMORY_SCOPE_WORKGROUP);
        }
      }
    }
    __syncthreads();
    // dense MFMA over this quarter; wave w covers local k [w*64, w*64+64)
#pragma unroll
    for (int s = 0; s < 2; ++s) {
      const int klb = w * 64 + s * 32 + e8;                 // 8-aligned local k
      const int sw = klb ^ ((row & 7) << 3);                // matches write swizzle
      const f32x4 wa = *reinterpret_cast<const f32x4*>(&W[row * 1024 + sw]);
      const f32x4 wb = *reinterpret_cast<const f32x4*>(&W[row * 1024 + (sw + 4)]);
      short8 af;
#pragma unroll
      for (int e = 0; e < 4; ++e) af[e] = (short)f2bf(wa[e]);
#pragma unroll
      for (int e = 0; e < 4; ++e) af[4 + e] = (short)f2bf(wb[e]);
      const int kabs = q * 1024 + klb;
      const u16* bp = xB + (size_t)(kabs >> 3) * 512 + (u32)(lane & 15) * 8;
      const short8 b0 = *reinterpret_cast<const short8*>(bp);
      const short8 b1 = *reinterpret_cast<const short8*>(bp + 128);
      const short8 b2 = *reinterpret_cast<const short8*>(bp + 256);
      const short8 b3 = *reinterpret_cast<const short8*>(bp + 384);
      acc0 = __builtin_amdgcn_mfma_f32_16x16x32_bf16(af, b0, acc0, 0, 0, 0);
      acc1 = __builtin_amdgcn_mfma_f32_16x16x32_bf16(af, b1, acc1, 0, 0, 0);
      acc2 = __builtin_amdgcn_mfma_f32_16x16x32_bf16(af, b2, acc2, 0, 0, 0);
      acc3 = __builtin_amdgcn_mfma_f32_16x16x32_bf16(af, b3, acc3, 0, 0, 0);
    }
  }
  __syncthreads();
  // write per-wave C partials to scratch: scr[((w*4+nt)*16 + crow)*16 + ccol]
  {
    const int ccol = lane & 15;                 // C col = lane&15 (m89-verified)
    const int rb = (lane >> 4) * 4;             // C row = (lane>>4)*4 + reg
#pragma unroll
    for (int qq = 0; qq < 4; ++qq) W[((w * 4 + 0) * 16 + rb + qq) * 16 + ccol] = acc0[qq];
#pragma unroll
    for (int qq = 0; qq < 4; ++qq) W[((w * 4 + 1) * 16 + rb + qq) * 16 + ccol] = acc1[qq];
#pragma unroll
    for (int qq = 0; qq < 4; ++qq) W[((w * 4 + 2) * 16 + rb + qq) * 16 + ccol] = acc2[qq];
#pragma unroll
    for (int qq = 0; qq < 4; ++qq) W[((w * 4 + 3) * 16 + rb + qq) * 16 + ccol] = acc3[qq];
  }
  __syncthreads();
  // reduce 16 wave-partials -> out(row rl, batch b); coalesced 64B store runs
  const int rl = tid & 15;
  const int b = tid >> 4;
  float sum = bias[t * 16u + rl];
#pragma unroll
  for (int w2 = 0; w2 < 16; ++w2)
    sum += W[((w2 * 4 + (b >> 4)) * 16 + rl) * 16 + (b & 15)];
  out[(size_t)b * OUT_F + t * 16u + rl] = sum;
}

// ---- fallback path (only if ws too small): correct but slow ----
__global__ __launch_bounds__(256) void k_bias_init(const float* __restrict__ bias,
                                                   float* __restrict__ out) {
  const int i = blockIdx.x * 256 + threadIdx.x;
  if (i < 64 * OUT_F) out[i] = bias[i & (OUT_F - 1)];
}

__global__ __launch_bounds__(256) void k_fallback(const int* __restrict__ rows,
                                                  const int* __restrict__ cols,
                                                  const float* __restrict__ vals,
                                                  const float* __restrict__ x,
                                                  float* __restrict__ out, int nnz) {
  const int gw = (int)(((u32)blockIdx.x * blockDim.x + threadIdx.x) >> 6);
  const int lane = threadIdx.x & 63;
  const int nw = (int)(((u32)gridDim.x * blockDim.x) >> 6);
  for (int i = gw; i < nnz; i += nw) {
    const int r = rows[i];
    const int c = cols[i];
    const float v = vals[i];
    const float xv = x[lane * IN_F + c];
    if (xv > THRESH) atomicAdd(&out[(size_t)lane * OUT_F + r], v * xv);
  }
}

extern "C" void kernel_launch(void* const* d_in, const int* in_sizes, int n_in,
                              void* d_out, int out_size, void* d_ws, size_t ws_size,
                              hipStream_t stream) {
  const float* x = (const float*)d_in[0];
  const int* rows = (const int*)d_in[1];
  const int* cols = (const int*)d_in[2];
  const float* vals = (const float*)d_in[3];
  const float* bias = (const float*)d_in[4];
  float* out = (float*)d_out;
  const int nnz = in_sizes[1];

  if (ws_size >= WS_NEEDED && nnz <= SBLOCKS * REC_PER_SB) {
    u16* xB = (u16*)((char*)d_ws + WS_XB);
    u32* offA = (u32*)((char*)d_ws + WS_OFFA);
    u32* sortg = (u32*)((char*)d_ws + WS_SORT);
    k_xb<<<128, 256, 0, stream>>>(x, xB);
    k_scatter<<<SBLOCKS, 1024, 0, stream>>>(rows, cols, vals, (u32)nnz, offA, sortg);
    k_accum<<<NBKT, 1024, 0, stream>>>(sortg, offA, xB, bias, out);
  } else {
    k_bias_init<<<(64 * OUT_F + 255) / 256, 256, 0, stream>>>(bias, out);
    k_fallback<<<4096, 256, 0, stream>>>(rows, cols, vals, x, out, nnz);
  }
}